// Round 1
// baseline (829.788 us; speedup 1.0000x reference)
//
#include <hip/hip_runtime.h>

// Problem constants: B=16, S=1024, d=1024, H=16, dh=64
#define B_  16
#define S_  1024
#define D_  1024
#define H_  16
#define DH_ 64
#define M_  (B_ * S_)    // 16384 rows in the projection GEMMs
#define BH_ (B_ * H_)    // 256 (b,h) pairs

typedef __attribute__((ext_vector_type(8))) __bf16 bf16x8;
typedef __attribute__((ext_vector_type(4))) float  f32x4;

__device__ __forceinline__ ushort f2bf(float f) {
  // round-to-nearest-even fp32 -> bf16
  unsigned u = __builtin_bit_cast(unsigned, f);
  return (ushort)((u + 0x7FFFu + ((u >> 16) & 1u)) >> 16);
}

__device__ __forceinline__ bf16x8 ld8(const ushort* p) {
  return *(const bf16x8*)p;  // 16B global/LDS load
}

__device__ __forceinline__ void gl_lds16(const void* g, void* s) {
  // async global->LDS, 16B per lane; dest = wave-uniform base + lane*16
  __builtin_amdgcn_global_load_lds((__attribute__((address_space(1))) void*)g,
                                   (__attribute__((address_space(3))) void*)s,
                                   16, 0, 0);
}

// ---------------------------------------------------------------- fp32->bf16
__global__ void cvt4(const float* __restrict__ s, ushort* __restrict__ d, int n4) {
  int i = blockIdx.x * 256 + threadIdx.x;
  if (i < n4) {
    const float4 v = ((const float4*)s)[i];
    ushort4 o;
    o.x = f2bf(v.x); o.y = f2bf(v.y); o.z = f2bf(v.z); o.w = f2bf(v.w);
    ((ushort4*)d)[i] = o;
  }
}

// -------------------------------------------------------------------- GEMM
// C[m,n] = sum_k A[m,k] * W[n,k] + bias[n]   (torch Linear: x @ W.T + b)
// A: [M,K] bf16 row-major, W: [N,K] bf16 row-major.
// MODE 0: out bf16 at [B,H,S,dh]   (Q, K)
// MODE 1: out bf16 at [B,H,dh,S]   (V transposed for PV's B-operand)
// MODE 2: out fp32 at [M,N]        (final projection -> d_out)
// m97 structure: 128x128 block tile, BK=32, 4 waves each 64x64 (4x4 x 16x16x32).
template <int MODE>
__global__ void gemm_bt(const ushort* __restrict__ A, const ushort* __restrict__ W,
                        const float* __restrict__ bias, ushort* __restrict__ outH,
                        float* __restrict__ outF, int M, int N, int K) {
  __shared__ ushort lA[128 * 32];
  __shared__ ushort lB[128 * 32];
  const int w  = threadIdx.x >> 6;
  const int l  = threadIdx.x & 63;
  const int m0 = blockIdx.y * 128, n0 = blockIdx.x * 128;
  // staging: lane covers (row = w*16 + l/4, col8 = (l%4)*8) -> LDS base + lane*16B
  const int srow = (w << 4) + (l >> 2);
  const int scol = (l & 3) << 3;
  const int lr = l & 15, qd = l >> 4;
  const int wm = (w >> 1) << 6, wn = (w & 1) << 6;

  const f32x4 z = {0.f, 0.f, 0.f, 0.f};
  f32x4 acc[4][4];
#pragma unroll
  for (int i = 0; i < 4; i++)
#pragma unroll
    for (int j = 0; j < 4; j++) acc[i][j] = z;

  for (int k0 = 0; k0 < K; k0 += 32) {
#pragma unroll
    for (int r = 0; r < 2; r++) {
      const int row = r * 64 + srow;
      gl_lds16(A + (size_t)(m0 + row) * K + k0 + scol, &lA[row * 32 + scol]);
      gl_lds16(W + (size_t)(n0 + row) * K + k0 + scol, &lB[row * 32 + scol]);
    }
    __syncthreads();
    bf16x8 af[4], bf_[4];
#pragma unroll
    for (int t = 0; t < 4; t++) {
      af[t]  = ld8(&lA[(wm + t * 16 + lr) * 32 + qd * 8]);
      bf_[t] = ld8(&lB[(wn + t * 16 + lr) * 32 + qd * 8]);
    }
#pragma unroll
    for (int i = 0; i < 4; i++)
#pragma unroll
      for (int j = 0; j < 4; j++)
        acc[i][j] = __builtin_amdgcn_mfma_f32_16x16x32_bf16(af[i], bf_[j], acc[i][j], 0, 0, 0);
    __syncthreads();
  }

  // epilogue: C/D layout col = lane&15, row = quad*4 + reg
#pragma unroll
  for (int j = 0; j < 4; j++) {
    const int n = n0 + wn + j * 16 + lr;
    const float bv = bias[n];
#pragma unroll
    for (int i = 0; i < 4; i++) {
      const f32x4 v = acc[i][j];
#pragma unroll
      for (int r = 0; r < 4; r++) {
        const int m = m0 + wm + i * 16 + qd * 4 + r;
        const float val = v[r] + bv;
        if (MODE == 2) {
          outF[(size_t)m * N + n] = val;
        } else {
          const int b = m >> 10, s = m & 1023, h = n >> 6, dc = n & 63;
          if (MODE == 0)
            outH[((size_t)(b * H_ + h) * S_ + s) * DH_ + dc] = f2bf(val);
          else
            outH[((size_t)(b * H_ + h) * DH_ + dc) * S_ + s] = f2bf(val);
        }
      }
    }
  }
}

// --------------------------------------------------------------- attention
// Flash-style causal attention. Q,K: [B,H,S,dh] bf16; Vt: [B,H,dh,S] bf16.
// Out: [B,S,H*dh] bf16 (ready as A for the O-projection GEMM).
// Block = 4 waves; wave w handles 16 query rows q0 = qt*64 + w*16.
__global__ void attn_kernel(const ushort* __restrict__ Q, const ushort* __restrict__ K,
                            const ushort* __restrict__ Vt, ushort* __restrict__ O) {
  __shared__ ushort lP[4 * 16 * 32];  // per-wave 16x32 P tile (C->A layout hop)
  const int bh = blockIdx.y, qt = blockIdx.x;
  const int w = threadIdx.x >> 6, l = threadIdx.x & 63;
  const int lr = l & 15, qd = l >> 4;
  const int q0 = qt * 64 + w * 16;
  const size_t base = (size_t)bh * (S_ * DH_);

  const ushort* qrow = Q + base + (size_t)(q0 + lr) * DH_;
  const bf16x8 qf0 = ld8(qrow + qd * 8);
  const bf16x8 qf1 = ld8(qrow + 32 + qd * 8);

  const f32x4 z = {0.f, 0.f, 0.f, 0.f};
  f32x4 o0 = z, o1 = z, o2 = z, o3 = z;
  float mi[4] = {-3e38f, -3e38f, -3e38f, -3e38f};
  float li[4] = {0.f, 0.f, 0.f, 0.f};

  ushort* myP = lP + w * (16 * 32);
  const int kend = qt * 64 + 64;  // block-uniform trip count (barrier-safe)
  const ushort* vbase = Vt + (size_t)bh * (DH_ * S_) + (size_t)lr * S_;

  for (int kb = 0; kb < kend; kb += 32) {
    const ushort* krow0 = K + base + (size_t)(kb + lr) * DH_;
    const ushort* krow1 = krow0 + 16 * DH_;
    f32x4 s0 = z, s1 = z;
    s0 = __builtin_amdgcn_mfma_f32_16x16x32_bf16(qf0, ld8(krow0 + qd * 8),      s0, 0, 0, 0);
    s0 = __builtin_amdgcn_mfma_f32_16x16x32_bf16(qf1, ld8(krow0 + 32 + qd * 8), s0, 0, 0, 0);
    s1 = __builtin_amdgcn_mfma_f32_16x16x32_bf16(qf0, ld8(krow1 + qd * 8),      s1, 0, 0, 0);
    s1 = __builtin_amdgcn_mfma_f32_16x16x32_bf16(qf1, ld8(krow1 + 32 + qd * 8), s1, 0, 0, 0);

    // online softmax; score rows = q0 + qd*4 + r, cols = kb(+16) + lr
#pragma unroll
    for (int r = 0; r < 4; r++) {
      const int gr = q0 + qd * 4 + r;
      float v0 = (kb + lr      <= gr) ? s0[r] * 0.125f : -1e30f;
      float v1 = (kb + 16 + lr <= gr) ? s1[r] * 0.125f : -1e30f;
      float mx = fmaxf(v0, v1);
      mx = fmaxf(mx, __shfl_xor(mx, 1));
      mx = fmaxf(mx, __shfl_xor(mx, 2));
      mx = fmaxf(mx, __shfl_xor(mx, 4));
      mx = fmaxf(mx, __shfl_xor(mx, 8));
      const float mnew = fmaxf(mi[r], mx);
      const float al = __expf(mi[r] - mnew);
      const float p0 = __expf(v0 - mnew);
      const float p1 = __expf(v1 - mnew);
      float rs = p0 + p1;
      rs += __shfl_xor(rs, 1);
      rs += __shfl_xor(rs, 2);
      rs += __shfl_xor(rs, 4);
      rs += __shfl_xor(rs, 8);
      li[r] = li[r] * al + rs;
      mi[r] = mnew;
      o0[r] *= al; o1[r] *= al; o2[r] *= al; o3[r] *= al;
      myP[(qd * 4 + r) * 32 + lr]      = f2bf(p0);
      myP[(qd * 4 + r) * 32 + 16 + lr] = f2bf(p1);
    }
    __syncthreads();  // order P writes (C-layout) before P reads (A-layout)
    const bf16x8 pf = ld8(&myP[lr * 32 + qd * 8]);
    o0 = __builtin_amdgcn_mfma_f32_16x16x32_bf16(pf, ld8(vbase + 0 * 16 * S_ + kb + qd * 8), o0, 0, 0, 0);
    o1 = __builtin_amdgcn_mfma_f32_16x16x32_bf16(pf, ld8(vbase + 1 * 16 * S_ + kb + qd * 8), o1, 0, 0, 0);
    o2 = __builtin_amdgcn_mfma_f32_16x16x32_bf16(pf, ld8(vbase + 2 * 16 * S_ + kb + qd * 8), o2, 0, 0, 0);
    o3 = __builtin_amdgcn_mfma_f32_16x16x32_bf16(pf, ld8(vbase + 3 * 16 * S_ + kb + qd * 8), o3, 0, 0, 0);
    __syncthreads();  // WAR: P reads done before next iter's writes
  }

  const int b = bh >> 4, h = bh & 15;
#pragma unroll
  for (int r = 0; r < 4; r++) {
    const int q = q0 + qd * 4 + r;
    const float inv = 1.f / li[r];
    const size_t rowb = ((size_t)(b * S_ + q) * D_) + h * 64;
    O[rowb + 0 * 16 + lr] = f2bf(o0[r] * inv);
    O[rowb + 1 * 16 + lr] = f2bf(o1[r] * inv);
    O[rowb + 2 * 16 + lr] = f2bf(o2[r] * inv);
    O[rowb + 3 * 16 + lr] = f2bf(o3[r] * inv);
  }
}

// ------------------------------------------------------------------- launch
extern "C" void kernel_launch(void* const* d_in, const int* in_sizes, int n_in,
                              void* d_out, int out_size, void* d_ws, size_t ws_size,
                              hipStream_t stream) {
  const float* x  = (const float*)d_in[0];
  const float* Wq = (const float*)d_in[1];
  const float* bq = (const float*)d_in[2];
  const float* Wk = (const float*)d_in[3];
  const float* bk = (const float*)d_in[4];
  const float* Wv = (const float*)d_in[5];
  const float* bv = (const float*)d_in[6];
  const float* Wo = (const float*)d_in[7];
  const float* bo = (const float*)d_in[8];
  float* out = (float*)d_out;

  char* ws = (char*)d_ws;
  ushort* xb   = (ushort*)(ws);                 // x bf16            32 MB
  ushort* qb   = (ushort*)(ws + 33554432);      // Q [B,H,S,dh]      32 MB
  ushort* kb   = (ushort*)(ws + 67108864);      // K [B,H,S,dh]      32 MB
  ushort* vtb  = (ushort*)(ws + 100663296);     // V [B,H,dh,S]      32 MB
  ushort* attn = (ushort*)(ws + 134217728);     // attn out [B,S,d]  32 MB
  ushort* wqb  = (ushort*)(ws + 167772160);     // weights bf16      2 MB each
  ushort* wkb  = (ushort*)(ws + 169869312);
  ushort* wvb  = (ushort*)(ws + 171966464);
  ushort* wob  = (ushort*)(ws + 174063616);

  cvt4<<<16384, 256, 0, stream>>>(x,  xb,  4194304);
  cvt4<<<1024,  256, 0, stream>>>(Wq, wqb, 262144);
  cvt4<<<1024,  256, 0, stream>>>(Wk, wkb, 262144);
  cvt4<<<1024,  256, 0, stream>>>(Wv, wvb, 262144);
  cvt4<<<1024,  256, 0, stream>>>(Wo, wob, 262144);

  dim3 g(D_ / 128, M_ / 128);  // (8, 128)
  gemm_bt<0><<<g, 256, 0, stream>>>(xb, wqb, bq, qb,  nullptr, M_, D_, D_);
  gemm_bt<0><<<g, 256, 0, stream>>>(xb, wkb, bk, kb,  nullptr, M_, D_, D_);
  gemm_bt<1><<<g, 256, 0, stream>>>(xb, wvb, bv, vtb, nullptr, M_, D_, D_);

  attn_kernel<<<dim3(S_ / 64, BH_), 256, 0, stream>>>(qb, kb, vtb, attn);

  gemm_bt<2><<<g, 256, 0, stream>>>(attn, wob, bo, nullptr, out, M_, D_, D_);
}

// Round 3
// 469.017 us; speedup vs baseline: 1.7692x; 1.7692x over previous
//
#include <hip/hip_runtime.h>

// Problem constants: B=16, S=1024, d=1024, H=16, dh=64
#define B_  16
#define S_  1024
#define D_  1024
#define H_  16
#define DH_ 64
#define M_  (B_ * S_)    // 16384 rows in the projection GEMMs
#define BH_ (B_ * H_)    // 256 (b,h) pairs

typedef __attribute__((ext_vector_type(8))) __bf16 bf16x8;
typedef __attribute__((ext_vector_type(4))) float  f32x4;

__device__ __forceinline__ ushort f2bf(float f) {
  // round-to-nearest-even fp32 -> bf16
  unsigned u = __builtin_bit_cast(unsigned, f);
  return (ushort)((u + 0x7FFFu + ((u >> 16) & 1u)) >> 16);
}

__device__ __forceinline__ bf16x8 ld8(const ushort* p) {
  return *(const bf16x8*)p;  // 16B global/LDS load
}

__device__ __forceinline__ float fast_exp2(float x) {
  return __builtin_amdgcn_exp2f(x);  // v_exp_f32 (input in log2 domain)
}

__device__ __forceinline__ void gl_lds16(const void* g, void* s) {
  // async global->LDS, 16B per lane; dest = wave-uniform base + lane*16
  __builtin_amdgcn_global_load_lds((__attribute__((address_space(1))) void*)g,
                                   (__attribute__((address_space(3))) void*)s,
                                   16, 0, 0);
}

// ---------------------------------------------------------------- fp32->bf16
__global__ void cvt4(const float* __restrict__ s, ushort* __restrict__ d, int n4) {
  int i = blockIdx.x * 256 + threadIdx.x;
  if (i < n4) {
    const float4 v = ((const float4*)s)[i];
    ushort4 o;
    o.x = f2bf(v.x); o.y = f2bf(v.y); o.z = f2bf(v.z); o.w = f2bf(v.w);
    ((ushort4*)d)[i] = o;
  }
}

// -------------------------------------------------------------------- GEMM
// C[m,n] = sum_k A[m,k] * W[n,k] + bias[n]   (torch Linear: x @ W.T + b)
// MODE 0: out bf16 at [B,H,S,dh]   (Q, K)
// MODE 1: out bf16 at [B,H,dh,S]   (V transposed for PV's A-operand)
// MODE 2: out fp32 at [M,N]        (final projection -> d_out)
template <int MODE>
__global__ void gemm_bt(const ushort* __restrict__ A, const ushort* __restrict__ W,
                        const float* __restrict__ bias, ushort* __restrict__ outH,
                        float* __restrict__ outF, int M, int N, int K) {
  __shared__ ushort lA[128 * 32];
  __shared__ ushort lB[128 * 32];
  const int w  = threadIdx.x >> 6;
  const int l  = threadIdx.x & 63;
  const int m0 = blockIdx.y * 128, n0 = blockIdx.x * 128;
  const int srow = (w << 4) + (l >> 2);
  const int scol = (l & 3) << 3;
  const int lr = l & 15, qd = l >> 4;
  const int wm = (w >> 1) << 6, wn = (w & 1) << 6;

  const f32x4 z = {0.f, 0.f, 0.f, 0.f};
  f32x4 acc[4][4];
#pragma unroll
  for (int i = 0; i < 4; i++)
#pragma unroll
    for (int j = 0; j < 4; j++) acc[i][j] = z;

  for (int k0 = 0; k0 < K; k0 += 32) {
#pragma unroll
    for (int r = 0; r < 2; r++) {
      const int row = r * 64 + srow;
      gl_lds16(A + (size_t)(m0 + row) * K + k0 + scol, &lA[row * 32 + scol]);
      gl_lds16(W + (size_t)(n0 + row) * K + k0 + scol, &lB[row * 32 + scol]);
    }
    __syncthreads();
    bf16x8 af[4], bf_[4];
#pragma unroll
    for (int t = 0; t < 4; t++) {
      af[t]  = ld8(&lA[(wm + t * 16 + lr) * 32 + qd * 8]);
      bf_[t] = ld8(&lB[(wn + t * 16 + lr) * 32 + qd * 8]);
    }
#pragma unroll
    for (int i = 0; i < 4; i++)
#pragma unroll
      for (int j = 0; j < 4; j++)
        acc[i][j] = __builtin_amdgcn_mfma_f32_16x16x32_bf16(af[i], bf_[j], acc[i][j], 0, 0, 0);
    __syncthreads();
  }

#pragma unroll
  for (int j = 0; j < 4; j++) {
    const int n = n0 + wn + j * 16 + lr;
    const float bv = bias[n];
#pragma unroll
    for (int i = 0; i < 4; i++) {
      const f32x4 v = acc[i][j];
#pragma unroll
      for (int r = 0; r < 4; r++) {
        const int m = m0 + wm + i * 16 + qd * 4 + r;
        const float val = v[r] + bv;
        if (MODE == 2) {
          outF[(size_t)m * N + n] = val;
        } else {
          const int b = m >> 10, s = m & 1023, h = n >> 6, dc = n & 63;
          if (MODE == 0)
            outH[((size_t)(b * H_ + h) * S_ + s) * DH_ + dc] = f2bf(val);
          else
            outH[((size_t)(b * H_ + h) * DH_ + dc) * S_ + s] = f2bf(val);
        }
      }
    }
  }
}

// --------------------------------------------------------------- attention
// Barrier-free causal flash attention, transposed-score formulation.
//   S^T = K @ Q^T  (A = K rows [S,dh], B = Q rows [S,dh]) -> C col = q, row = key
//   no-max softmax: p = exp2(s * log2(e)/8); masked -> 0. li summed per lane,
//   reduced once at the end (2 shfl_xor).
//   P^T packed bf16 in wave-private LDS [q][key] via ds_write_b64 (keys are
//   consecutive per lane in S^T C-layout), read back as PV B-operand b128.
//   O^T = V^T @ P^T (A = Vt rows [dh,S]) -> C col = q, row = dh; dh contiguous
//   per lane -> coalesced dwordx2 epilogue stores. No __syncthreads anywhere.
// Each wave owns 64 q rows; 32 keys per iteration.
#define PSTR 40  // LDS row stride (ushorts): 80B, 16B-aligned, conflict-min
__global__ __launch_bounds__(256) void attn_kernel(
    const ushort* __restrict__ Q, const ushort* __restrict__ K,
    const ushort* __restrict__ Vt, ushort* __restrict__ O) {
  __shared__ ushort lP[4][64 * PSTR];
  const int bh = blockIdx.y;
  const int w = threadIdx.x >> 6, l = threadIdx.x & 63;
  const int lr = l & 15, qd = l >> 4;
  const int q0 = (blockIdx.x * 4 + w) * 64;
  const size_t base = (size_t)bh * (S_ * DH_);
  const ushort* Qb = Q + base;
  const ushort* Kb = K + base;
  const ushort* Vb = Vt + (size_t)bh * (DH_ * S_);
  ushort* myP = &lP[w][0];

  // Q B-fragments (held for the whole loop): B[n=q(lane&15)][k=dh qd*8+j]
  bf16x8 bq[4][2];
#pragma unroll
  for (int qt = 0; qt < 4; qt++)
#pragma unroll
    for (int kc = 0; kc < 2; kc++)
      bq[qt][kc] = ld8(Qb + (size_t)(q0 + qt * 16 + lr) * DH_ + kc * 32 + qd * 8);

  const f32x4 z = {0.f, 0.f, 0.f, 0.f};
  f32x4 acc[4][4];  // [dh tile][q tile], O^T C-layout
#pragma unroll
  for (int i = 0; i < 4; i++)
#pragma unroll
    for (int j = 0; j < 4; j++) acc[i][j] = z;
  float li[4] = {0.f, 0.f, 0.f, 0.f};

  const float C = 0.18033688011112042f;  // log2(e) / sqrt(dh)

  for (int kb = 0; kb < q0 + 64; kb += 32) {
    // K A-frags: A[m=key local (lane&15)][k=dh qd*8+j]
    bf16x8 ak[2][2];
#pragma unroll
    for (int kt = 0; kt < 2; kt++)
#pragma unroll
      for (int kc = 0; kc < 2; kc++)
        ak[kt][kc] = ld8(Kb + (size_t)(kb + kt * 16 + lr) * DH_ + kc * 32 + qd * 8);
    // V A-frags: A[m=dh local][k=key qd*8+j]
    bf16x8 av[4];
#pragma unroll
    for (int dt = 0; dt < 4; dt++)
      av[dt] = ld8(Vb + (size_t)(dt * 16 + lr) * S_ + kb + qd * 8);

    const bool diag = (kb + 31 >= q0);  // wave-uniform: mask needed
#pragma unroll
    for (int kt = 0; kt < 2; kt++) {
      const int keyb = kb + kt * 16 + qd * 4;
#pragma unroll
      for (int qt = 0; qt < 4; qt++) {
        f32x4 s = z;
        s = __builtin_amdgcn_mfma_f32_16x16x32_bf16(ak[kt][0], bq[qt][0], s, 0, 0, 0);
        s = __builtin_amdgcn_mfma_f32_16x16x32_bf16(ak[kt][1], bq[qt][1], s, 0, 0, 0);
        const int qq = q0 + qt * 16 + lr;
        float e0 = s[0] * C, e1 = s[1] * C, e2 = s[2] * C, e3 = s[3] * C;
        if (diag) {
          e0 = (keyb + 0 <= qq) ? e0 : -1e30f;
          e1 = (keyb + 1 <= qq) ? e1 : -1e30f;
          e2 = (keyb + 2 <= qq) ? e2 : -1e30f;
          e3 = (keyb + 3 <= qq) ? e3 : -1e30f;
        }
        const float p0 = fast_exp2(e0), p1 = fast_exp2(e1);
        const float p2 = fast_exp2(e2), p3 = fast_exp2(e3);
        li[qt] += (p0 + p1) + (p2 + p3);
        // truncation-pack to bf16x2 pairs (keys ascending), wave-private LDS
        const uint d0 = __builtin_amdgcn_perm(__builtin_bit_cast(uint, p1),
                                              __builtin_bit_cast(uint, p0), 0x07060302u);
        const uint d1 = __builtin_amdgcn_perm(__builtin_bit_cast(uint, p3),
                                              __builtin_bit_cast(uint, p2), 0x07060302u);
        uint2 pk; pk.x = d0; pk.y = d1;
        *(uint2*)(myP + (qt * 16 + lr) * PSTR + kt * 16 + qd * 4) = pk;
      }
    }
    // PV: B[n=q][k=key qd*8+j] from LDS (same-wave dep; compiler emits lgkmcnt)
#pragma unroll
    for (int qt = 0; qt < 4; qt++) {
      const bf16x8 bp = ld8(myP + (qt * 16 + lr) * PSTR + qd * 8);
#pragma unroll
      for (int dt = 0; dt < 4; dt++)
        acc[dt][qt] = __builtin_amdgcn_mfma_f32_16x16x32_bf16(av[dt], bp, acc[dt][qt], 0, 0, 0);
    }
  }

  // li reduction across the 4 quad-groups, then epilogue
  const int b = bh >> 4, h = bh & 15;
#pragma unroll
  for (int qt = 0; qt < 4; qt++) {
    float s = li[qt];
    s += __shfl_xor(s, 16);
    s += __shfl_xor(s, 32);
    const float inv = 1.f / s;
    const int q = q0 + qt * 16 + lr;
    ushort* orow = O + ((size_t)(b * S_ + q) * D_) + h * DH_ + qd * 4;
#pragma unroll
    for (int dt = 0; dt < 4; dt++) {
      const f32x4 v = acc[dt][qt];
      uint2 pk;
      pk.x = (uint)f2bf(v[0] * inv) | ((uint)f2bf(v[1] * inv) << 16);
      pk.y = (uint)f2bf(v[2] * inv) | ((uint)f2bf(v[3] * inv) << 16);
      *(uint2*)(orow + dt * 16) = pk;
    }
  }
}

// ------------------------------------------------------------------- launch
extern "C" void kernel_launch(void* const* d_in, const int* in_sizes, int n_in,
                              void* d_out, int out_size, void* d_ws, size_t ws_size,
                              hipStream_t stream) {
  const float* x  = (const float*)d_in[0];
  const float* Wq = (const float*)d_in[1];
  const float* bq = (const float*)d_in[2];
  const float* Wk = (const float*)d_in[3];
  const float* bk = (const float*)d_in[4];
  const float* Wv = (const float*)d_in[5];
  const float* bv = (const float*)d_in[6];
  const float* Wo = (const float*)d_in[7];
  const float* bo = (const float*)d_in[8];
  float* out = (float*)d_out;

  char* ws = (char*)d_ws;
  ushort* xb   = (ushort*)(ws);                 // x bf16            32 MB
  ushort* qb   = (ushort*)(ws + 33554432);      // Q [B,H,S,dh]      32 MB
  ushort* kb   = (ushort*)(ws + 67108864);      // K [B,H,S,dh]      32 MB
  ushort* vtb  = (ushort*)(ws + 100663296);     // V [B,H,dh,S]      32 MB
  ushort* attn = (ushort*)(ws + 134217728);     // attn out [B,S,d]  32 MB
  ushort* wqb  = (ushort*)(ws + 167772160);     // weights bf16      2 MB each
  ushort* wkb  = (ushort*)(ws + 169869312);
  ushort* wvb  = (ushort*)(ws + 171966464);
  ushort* wob  = (ushort*)(ws + 174063616);

  cvt4<<<16384, 256, 0, stream>>>(x,  xb,  4194304);
  cvt4<<<1024,  256, 0, stream>>>(Wq, wqb, 262144);
  cvt4<<<1024,  256, 0, stream>>>(Wk, wkb, 262144);
  cvt4<<<1024,  256, 0, stream>>>(Wv, wvb, 262144);
  cvt4<<<1024,  256, 0, stream>>>(Wo, wob, 262144);

  dim3 g(D_ / 128, M_ / 128);  // (8, 128)
  gemm_bt<0><<<g, 256, 0, stream>>>(xb, wqb, bq, qb,  nullptr, M_, D_, D_);
  gemm_bt<0><<<g, 256, 0, stream>>>(xb, wkb, bk, kb,  nullptr, M_, D_, D_);
  gemm_bt<1><<<g, 256, 0, stream>>>(xb, wvb, bv, vtb, nullptr, M_, D_, D_);

  attn_kernel<<<dim3(4, BH_), 256, 0, stream>>>(qb, kb, vtb, attn);

  gemm_bt<2><<<g, 256, 0, stream>>>(attn, wob, bo, nullptr, out, M_, D_, D_);
}

// Round 4
// 426.321 us; speedup vs baseline: 1.9464x; 1.1001x over previous
//
#include <hip/hip_runtime.h>

// Problem constants: B=16, S=1024, d=1024, H=16, dh=64
#define B_  16
#define S_  1024
#define D_  1024
#define H_  16
#define DH_ 64
#define M_  (B_ * S_)    // 16384 rows in the projection GEMMs
#define BH_ (B_ * H_)    // 256 (b,h) pairs

typedef __attribute__((ext_vector_type(8))) __bf16 bf16x8;
typedef __attribute__((ext_vector_type(4))) float  f32x4;

__device__ __forceinline__ ushort f2bf(float f) {
  unsigned u = __builtin_bit_cast(unsigned, f);
  return (ushort)((u + 0x7FFFu + ((u >> 16) & 1u)) >> 16);
}

__device__ __forceinline__ bf16x8 ld8(const ushort* p) {
  return *(const bf16x8*)p;
}

__device__ __forceinline__ float fast_exp2(float x) {
  return __builtin_amdgcn_exp2f(x);  // v_exp_f32
}

__device__ __forceinline__ void gl_lds16(const void* g, void* s) {
  __builtin_amdgcn_global_load_lds((__attribute__((address_space(1))) void*)g,
                                   (__attribute__((address_space(3))) void*)s,
                                   16, 0, 0);
}

// ---------------------------------------------------------------- fp32->bf16
__global__ void cvt4(const float* __restrict__ s, ushort* __restrict__ d, int n4) {
  int i = blockIdx.x * 256 + threadIdx.x;
  if (i < n4) {
    const float4 v = ((const float4*)s)[i];
    ushort4 o;
    o.x = f2bf(v.x); o.y = f2bf(v.y); o.z = f2bf(v.z); o.w = f2bf(v.w);
    ((ushort4*)d)[i] = o;
  }
}

// ------------------------------------------------------- fused QKV projection
// One GEMM over concatenated weights Wqkv [3072,1024] (wq|wk|wv contiguous).
// Epilogue routes by n-block: proj 0 -> Q [B,H,S,dh], 1 -> K [B,H,S,dh],
// 2 -> V^T [B,H,dh,S]. n-block (128) never straddles a projection boundary.
__global__ void gemm_qkv(const ushort* __restrict__ A, const ushort* __restrict__ Wqkv,
                         const float* __restrict__ bqp, const float* __restrict__ bkp,
                         const float* __restrict__ bvp, ushort* __restrict__ qO,
                         ushort* __restrict__ kO, ushort* __restrict__ vtO) {
  __shared__ ushort lA[128 * 32];
  __shared__ ushort lB[128 * 32];
  const int w  = threadIdx.x >> 6;
  const int l  = threadIdx.x & 63;
  const int m0 = blockIdx.y * 128, n0 = blockIdx.x * 128;
  const int srow = (w << 4) + (l >> 2);
  const int scol = (l & 3) << 3;
  const int lr = l & 15, qd = l >> 4;
  const int wm = (w >> 1) << 6, wn = (w & 1) << 6;
  const int K = D_;

  const f32x4 z = {0.f, 0.f, 0.f, 0.f};
  f32x4 acc[4][4];
#pragma unroll
  for (int i = 0; i < 4; i++)
#pragma unroll
    for (int j = 0; j < 4; j++) acc[i][j] = z;

  for (int k0 = 0; k0 < K; k0 += 32) {
#pragma unroll
    for (int r = 0; r < 2; r++) {
      const int row = r * 64 + srow;
      gl_lds16(A    + (size_t)(m0 + row) * K + k0 + scol, &lA[row * 32 + scol]);
      gl_lds16(Wqkv + (size_t)(n0 + row) * K + k0 + scol, &lB[row * 32 + scol]);
    }
    __syncthreads();
    bf16x8 af[4], bf_[4];
#pragma unroll
    for (int t = 0; t < 4; t++) {
      af[t]  = ld8(&lA[(wm + t * 16 + lr) * 32 + qd * 8]);
      bf_[t] = ld8(&lB[(wn + t * 16 + lr) * 32 + qd * 8]);
    }
#pragma unroll
    for (int i = 0; i < 4; i++)
#pragma unroll
      for (int j = 0; j < 4; j++)
        acc[i][j] = __builtin_amdgcn_mfma_f32_16x16x32_bf16(af[i], bf_[j], acc[i][j], 0, 0, 0);
    __syncthreads();
  }

  const int proj = n0 >> 10;                       // wave-uniform 0/1/2
  const float* bias = (proj == 0) ? bqp : (proj == 1) ? bkp : bvp;
  ushort* outH = (proj == 0) ? qO : (proj == 1) ? kO : vtO;
  const int nb = n0 & 1023;

#pragma unroll
  for (int j = 0; j < 4; j++) {
    const int n = nb + wn + j * 16 + lr;
    const float bv = bias[n];
    const int h = n >> 6, dc = n & 63;
#pragma unroll
    for (int i = 0; i < 4; i++) {
      const f32x4 v = acc[i][j];
#pragma unroll
      for (int r = 0; r < 4; r++) {
        const int m = m0 + wm + i * 16 + qd * 4 + r;
        const int b = m >> 10, s = m & 1023;
        const float val = v[r] + bv;
        if (proj < 2)
          outH[((size_t)(b * H_ + h) * S_ + s) * DH_ + dc] = f2bf(val);
        else
          outH[((size_t)(b * H_ + h) * DH_ + dc) * S_ + s] = f2bf(val);
      }
    }
  }
}

// ------------------------------------------------------------- output GEMM
// out[m,n] = sum_k A[m,k] * W[n,k] + bias[n], fp32 out.
__global__ void gemm_out(const ushort* __restrict__ A, const ushort* __restrict__ W,
                         const float* __restrict__ bias, float* __restrict__ outF) {
  __shared__ ushort lA[128 * 32];
  __shared__ ushort lB[128 * 32];
  const int w  = threadIdx.x >> 6;
  const int l  = threadIdx.x & 63;
  const int m0 = blockIdx.y * 128, n0 = blockIdx.x * 128;
  const int srow = (w << 4) + (l >> 2);
  const int scol = (l & 3) << 3;
  const int lr = l & 15, qd = l >> 4;
  const int wm = (w >> 1) << 6, wn = (w & 1) << 6;
  const int K = D_, N = D_;

  const f32x4 z = {0.f, 0.f, 0.f, 0.f};
  f32x4 acc[4][4];
#pragma unroll
  for (int i = 0; i < 4; i++)
#pragma unroll
    for (int j = 0; j < 4; j++) acc[i][j] = z;

  for (int k0 = 0; k0 < K; k0 += 32) {
#pragma unroll
    for (int r = 0; r < 2; r++) {
      const int row = r * 64 + srow;
      gl_lds16(A + (size_t)(m0 + row) * K + k0 + scol, &lA[row * 32 + scol]);
      gl_lds16(W + (size_t)(n0 + row) * K + k0 + scol, &lB[row * 32 + scol]);
    }
    __syncthreads();
    bf16x8 af[4], bf_[4];
#pragma unroll
    for (int t = 0; t < 4; t++) {
      af[t]  = ld8(&lA[(wm + t * 16 + lr) * 32 + qd * 8]);
      bf_[t] = ld8(&lB[(wn + t * 16 + lr) * 32 + qd * 8]);
    }
#pragma unroll
    for (int i = 0; i < 4; i++)
#pragma unroll
      for (int j = 0; j < 4; j++)
        acc[i][j] = __builtin_amdgcn_mfma_f32_16x16x32_bf16(af[i], bf_[j], acc[i][j], 0, 0, 0);
    __syncthreads();
  }

#pragma unroll
  for (int j = 0; j < 4; j++) {
    const int n = n0 + wn + j * 16 + lr;
    const float bv = bias[n];
#pragma unroll
    for (int i = 0; i < 4; i++) {
      const f32x4 v = acc[i][j];
#pragma unroll
      for (int r = 0; r < 4; r++) {
        const int m = m0 + wm + i * 16 + qd * 4 + r;
        outF[(size_t)m * N + n] = v[r] + bv;
      }
    }
  }
}

// --------------------------------------------------------------- attention
// Barrier-free causal flash attention (transposed-score formulation) with
// balanced wave pairing: wave p handles q-tiles p and 15-p (k-iters
// (2p+2)+(32-2p) = 34 for every wave -> no tail imbalance).
// Grid (2, BH): 512 blocks, 2 blocks/CU co-resident = 16 waves/CU sustained.
#define PSTR 40  // LDS row stride (ushorts): 80B, 16B-aligned
__global__ __launch_bounds__(256) void attn_kernel(
    const ushort* __restrict__ Q, const ushort* __restrict__ K,
    const ushort* __restrict__ Vt, ushort* __restrict__ O) {
  __shared__ ushort lP[4][64 * PSTR];
  const int bh = blockIdx.y;
  const int w = threadIdx.x >> 6, l = threadIdx.x & 63;
  const int lr = l & 15, qd = l >> 4;
  const int p = blockIdx.x * 4 + w;  // 0..7
  const size_t base = (size_t)bh * (S_ * DH_);
  const ushort* Qb = Q + base;
  const ushort* Kb = K + base;
  const ushort* Vb = Vt + (size_t)bh * (DH_ * S_);
  ushort* myP = &lP[w][0];
  const int b = bh >> 4, h = bh & 15;
  const float C = 0.18033688011112042f;  // log2(e) / sqrt(dh)
  const f32x4 z = {0.f, 0.f, 0.f, 0.f};

#pragma unroll 1
  for (int tt = 0; tt < 2; tt++) {
    const int q0 = (tt == 0 ? p : 15 - p) * 64;

    // Q B-fragments: B[n=q(lane&15)][k=dh qd*8+j]
    bf16x8 bq[4][2];
#pragma unroll
    for (int qt = 0; qt < 4; qt++)
#pragma unroll
      for (int kc = 0; kc < 2; kc++)
        bq[qt][kc] = ld8(Qb + (size_t)(q0 + qt * 16 + lr) * DH_ + kc * 32 + qd * 8);

    f32x4 acc[4][4];  // [dh tile][q tile], O^T C-layout
#pragma unroll
    for (int i = 0; i < 4; i++)
#pragma unroll
      for (int j = 0; j < 4; j++) acc[i][j] = z;
    float li[4] = {0.f, 0.f, 0.f, 0.f};

    for (int kb = 0; kb < q0 + 64; kb += 32) {
      // K A-frags: A[m=key local][k=dh]
      bf16x8 ak[2][2];
#pragma unroll
      for (int kt = 0; kt < 2; kt++)
#pragma unroll
        for (int kc = 0; kc < 2; kc++)
          ak[kt][kc] = ld8(Kb + (size_t)(kb + kt * 16 + lr) * DH_ + kc * 32 + qd * 8);
      // V A-frags: A[m=dh local][k=key]
      bf16x8 av[4];
#pragma unroll
      for (int dt = 0; dt < 4; dt++)
        av[dt] = ld8(Vb + (size_t)(dt * 16 + lr) * S_ + kb + qd * 8);

      const bool diag = (kb + 31 >= q0);  // wave-uniform
#pragma unroll
      for (int kt = 0; kt < 2; kt++) {
        const int keyb = kb + kt * 16 + qd * 4;
#pragma unroll
        for (int qt = 0; qt < 4; qt++) {
          f32x4 s = z;
          s = __builtin_amdgcn_mfma_f32_16x16x32_bf16(ak[kt][0], bq[qt][0], s, 0, 0, 0);
          s = __builtin_amdgcn_mfma_f32_16x16x32_bf16(ak[kt][1], bq[qt][1], s, 0, 0, 0);
          const int qq = q0 + qt * 16 + lr;
          float e0 = s[0] * C, e1 = s[1] * C, e2 = s[2] * C, e3 = s[3] * C;
          if (diag) {
            e0 = (keyb + 0 <= qq) ? e0 : -1e30f;
            e1 = (keyb + 1 <= qq) ? e1 : -1e30f;
            e2 = (keyb + 2 <= qq) ? e2 : -1e30f;
            e3 = (keyb + 3 <= qq) ? e3 : -1e30f;
          }
          const float p0 = fast_exp2(e0), p1 = fast_exp2(e1);
          const float p2 = fast_exp2(e2), p3 = fast_exp2(e3);
          li[qt] += (p0 + p1) + (p2 + p3);
          const uint d0 = __builtin_amdgcn_perm(__builtin_bit_cast(uint, p1),
                                                __builtin_bit_cast(uint, p0), 0x07060302u);
          const uint d1 = __builtin_amdgcn_perm(__builtin_bit_cast(uint, p3),
                                                __builtin_bit_cast(uint, p2), 0x07060302u);
          uint2 pk; pk.x = d0; pk.y = d1;
          *(uint2*)(myP + (qt * 16 + lr) * PSTR + kt * 16 + qd * 4) = pk;
        }
      }
      // PV: B[n=q][k=key] from wave-private LDS
#pragma unroll
      for (int qt = 0; qt < 4; qt++) {
        const bf16x8 bp = ld8(myP + (qt * 16 + lr) * PSTR + qd * 8);
#pragma unroll
        for (int dt = 0; dt < 4; dt++)
          acc[dt][qt] = __builtin_amdgcn_mfma_f32_16x16x32_bf16(av[dt], bp, acc[dt][qt], 0, 0, 0);
      }
    }

    // epilogue for this tile
#pragma unroll
    for (int qt = 0; qt < 4; qt++) {
      float s = li[qt];
      s += __shfl_xor(s, 16);
      s += __shfl_xor(s, 32);
      const float inv = 1.f / s;
      const int q = q0 + qt * 16 + lr;
      ushort* orow = O + ((size_t)(b * S_ + q) * D_) + h * DH_ + qd * 4;
#pragma unroll
      for (int dt = 0; dt < 4; dt++) {
        const f32x4 v = acc[dt][qt];
        uint2 pk;
        pk.x = (uint)f2bf(v[0] * inv) | ((uint)f2bf(v[1] * inv) << 16);
        pk.y = (uint)f2bf(v[2] * inv) | ((uint)f2bf(v[3] * inv) << 16);
        *(uint2*)(orow + dt * 16) = pk;
      }
    }
  }
}

// ------------------------------------------------------------------- launch
extern "C" void kernel_launch(void* const* d_in, const int* in_sizes, int n_in,
                              void* d_out, int out_size, void* d_ws, size_t ws_size,
                              hipStream_t stream) {
  const float* x  = (const float*)d_in[0];
  const float* Wq = (const float*)d_in[1];
  const float* bq = (const float*)d_in[2];
  const float* Wk = (const float*)d_in[3];
  const float* bk = (const float*)d_in[4];
  const float* Wv = (const float*)d_in[5];
  const float* bv = (const float*)d_in[6];
  const float* Wo = (const float*)d_in[7];
  const float* bo = (const float*)d_in[8];
  float* out = (float*)d_out;

  char* ws = (char*)d_ws;
  ushort* xb   = (ushort*)(ws);                 // x bf16            32 MB
  ushort* qb   = (ushort*)(ws + 33554432);      // Q [B,H,S,dh]      32 MB
  ushort* kb   = (ushort*)(ws + 67108864);      // K [B,H,S,dh]      32 MB
  ushort* vtb  = (ushort*)(ws + 100663296);     // V [B,H,dh,S]      32 MB
  ushort* attn = (ushort*)(ws + 134217728);     // attn out [B,S,d]  32 MB
  ushort* wqb  = (ushort*)(ws + 167772160);     // Wq|Wk|Wv contiguous: [3072,1024]
  ushort* wkb  = (ushort*)(ws + 169869312);
  ushort* wvb  = (ushort*)(ws + 171966464);
  ushort* wob  = (ushort*)(ws + 174063616);

  cvt4<<<16384, 256, 0, stream>>>(x,  xb,  4194304);
  cvt4<<<1024,  256, 0, stream>>>(Wq, wqb, 262144);
  cvt4<<<1024,  256, 0, stream>>>(Wk, wkb, 262144);
  cvt4<<<1024,  256, 0, stream>>>(Wv, wvb, 262144);
  cvt4<<<1024,  256, 0, stream>>>(Wo, wob, 262144);

  gemm_qkv<<<dim3(24, 128), 256, 0, stream>>>(xb, wqb, bq, bk, bv, qb, kb, vtb);

  attn_kernel<<<dim3(2, BH_), 256, 0, stream>>>(qb, kb, vtb, attn);

  gemm_out<<<dim3(8, 128), 256, 0, stream>>>(attn, wob, bo, out);
}